// Round 16
// baseline (52.499 us; speedup 1.0000x reference)
//
#include <hip/hip_runtime.h>

// ResidualVQ forward: out[n] = codebook[argmin_k(-2 x.c_k + ||c_k||^2)]
// v16: m97-style 2-phase LDS-staged GEMM, density-first.
//  - TC=128 codes/tile (32 KB bf16, fragment-linear) staged once per block
//    via global_load_lds, double-buffered; 8 tiles, 8 barriers total.
//  - per wave per tile: 32 ds_read_b128 -> 64 MFMA in 8 INDEPENDENT chains
//    (8 cf x [4 ks x 2 split-terms]) -> 4x MFMA density + 4x chain ILP vs v13.
//  - numerics identical to v13 (x = xh+xl split vs bf16-hi codebook,
//    MARGIN=3.25 margin-list + exact fp32 recheck, register running-min).

typedef short bfrag __attribute__((ext_vector_type(8)));  // 8 bf16 = 4 VGPR
typedef float f32x4 __attribute__((ext_vector_type(4)));

constexpr int D = 128;      // embedding dim
constexpr int BR = 64;      // rows per block -> grid 512 = 2 blocks/CU (LDS-capped)
constexpr int NTH = 256;    // 4 waves; wave w owns rows w*16..w*16+15
constexpr int TC = 128;     // codes per LDS tile
constexpr int NTILE = 8;    // 1024 / 128
constexpr int LCAP = 1024;  // candidate capacity per block
#define MARGIN 3.25f        // > 2 * max |approx dist err| (x split; cb bf16)

__device__ __forceinline__ unsigned fenc(float f) {  // order-preserving f32->u32
    unsigned u = __float_as_uint(f);
    return (u & 0x80000000u) ? ~u : (u | 0x80000000u);
}
__device__ __forceinline__ unsigned cvtpk(float a, float b) {
    unsigned r;
    asm("v_cvt_pk_bf16_f32 %0, %1, %2" : "=v"(r) : "v"(a), "v"(b));
    return r;
}
union FU { bfrag v; unsigned u[4]; };

// 8 fp32 -> bf16 hi fragment + bf16 lo (residual) fragment
__device__ __forceinline__ void conv8(const float* f, bfrag& hi, bfrag& lo) {
    FU h, l;
#pragma unroll
    for (int m = 0; m < 4; ++m) {
        float a = f[2 * m], b = f[2 * m + 1];
        unsigned hp = cvtpk(a, b);
        float ra = a - __uint_as_float(hp << 16);
        float rb = b - __uint_as_float(hp & 0xFFFF0000u);
        h.u[m] = hp;
        l.u[m] = cvtpk(ra, rb);
    }
    hi = h.v;
    lo = l.v;
}

// --- prep: exact cnorm (K threads) + bf16 fragment cast (K*16 threads) ---
// Fragment t (= cg*256 + ks*64 + lane, lane=kg*16+la) holds
// cb[cg*16+la][ks*32+kg*8 .. +7], bf16 RN. Coalesced 16B writes.
__global__ __launch_bounds__(256) void prep_kernel(const float* __restrict__ cb,
                                                   float* __restrict__ cnorm,
                                                   short* __restrict__ hi, int K) {
    const int tg = blockIdx.x * 256 + threadIdx.x;  // 0..16383
    {
        const int cg = tg >> 8;
        const int r = tg & 255;
        const int ks = r >> 6;
        const int lane = r & 63;
        const int kg = lane >> 4, la = lane & 15;
        const float* src = cb + (size_t)(cg * 16 + la) * D + ks * 32 + kg * 8;
        float4 f0 = *(const float4*)src;
        float4 f1 = *(const float4*)(src + 4);
        FU h;
        h.u[0] = cvtpk(f0.x, f0.y);
        h.u[1] = cvtpk(f0.z, f0.w);
        h.u[2] = cvtpk(f1.x, f1.y);
        h.u[3] = cvtpk(f1.z, f1.w);
        ((bfrag*)hi)[tg] = h.v;
    }
    if (tg < K) {
        const float4* c = (const float4*)(cb + (size_t)tg * D);
        float s0 = 0.f, s1 = 0.f, s2 = 0.f, s3 = 0.f;
#pragma unroll
        for (int i = 0; i < D / 4; ++i) {
            float4 v = c[i];
            s0 = fmaf(v.x, v.x, s0);
            s1 = fmaf(v.y, v.y, s1);
            s2 = fmaf(v.z, v.z, s2);
            s3 = fmaf(v.w, v.w, s3);
        }
        cnorm[tg] = (s0 + s1) + (s2 + s3);
    }
}

__global__ __launch_bounds__(NTH) void vq_mfma(const float* __restrict__ x,
                                               const float* __restrict__ cb,
                                               const short* __restrict__ cbh,
                                               const float* __restrict__ cnorm,
                                               float* __restrict__ out,
                                               int N, int K) {
    __shared__ short cbt[2][TC * D];     // 2 x 32 KB, fragment-linear
    __shared__ float cns[1024];          // 4 KB
    __shared__ unsigned clist[LCAP];     // 4 KB
    __shared__ unsigned long long win[BR];
    __shared__ int ccnt;
    // ~73 KB -> 2 blocks/CU

    const int tid = threadIdx.x;
    const int lane = tid & 63;
    const int wv = tid >> 6;   // 0..3 = row-group (16 rows each)
    const int la = lane & 15;
    const int kg = lane >> 4;
    const int row0 = blockIdx.x * BR;

    if (tid < BR) win[tid] = ~0ull;
    if (tid == 0) ccnt = 0;
    for (int i = tid; i < K; i += NTH) cns[i] = cnorm[i];

    // ---- (-2x) -> split-bf16 B-fragments in registers (col=la=row, k=kg*8+j) ----
    bfrag xh[4], xl[4];
    {
        const int xrow = row0 + wv * 16 + la;
        const float* xp = x + (size_t)xrow * D + kg * 8;
#pragma unroll
        for (int ks = 0; ks < 4; ++ks) {
            float4 f0 = *(const float4*)(xp + ks * 32);
            float4 f1 = *(const float4*)(xp + ks * 32 + 4);
            float v[8] = {-2.f * f0.x, -2.f * f0.y, -2.f * f0.z, -2.f * f0.w,
                          -2.f * f1.x, -2.f * f1.y, -2.f * f1.z, -2.f * f1.w};
            conv8(v, xh[ks], xl[ks]);
        }
    }

    // ---- tile staging: 32 KB fragment-linear, pure global_load_lds ----
    // issue i of wave wv moves bytes [(wv*8+i)*1024 .. +1023] of the tile.
    auto stage = [&](int t, int buf) {
        const char* g = (const char*)cbh + (size_t)t * 32768 + wv * 8192 + lane * 16;
        char* l = (char*)&cbt[buf][0] + wv * 8192;  // wave-uniform base (+lane*16 HW)
#pragma unroll
        for (int i = 0; i < 8; ++i) {
            __builtin_amdgcn_global_load_lds(
                (const __attribute__((address_space(1))) uint32_t*)(g + i * 1024),
                (__attribute__((address_space(3))) uint32_t*)(l + i * 1024), 16, 0, 0);
        }
    };

    stage(0, 0);
    __syncthreads();

    const int row = wv * 16 + la;  // block-local row this lane owns
    float rm = 3.4e38f;            // running approx row-min (register)

    for (int t = 0; t < NTILE; ++t) {
        const int buf = t & 1;
        if (t + 1 < NTILE) stage(t + 1, buf ^ 1);  // loads fly under the MFMAs

        // ---- compute: 8 cf x {4 ds_read_b128, 8 MFMA} = 8 independent chains ----
        const short* ph = &cbt[buf][0];
        f32x4 acc[8];
#pragma unroll
        for (int cf = 0; cf < 8; ++cf) {
            acc[cf] = *(const f32x4*)&cns[t * TC + cf * 16 + kg * 4];  // cn folded in
            bfrag bh[4];
#pragma unroll
            for (int ks = 0; ks < 4; ++ks)
                bh[ks] = *(const bfrag*)(ph + cf * 2048 + ks * 512 + lane * 8);
#pragma unroll
            for (int ks = 0; ks < 4; ++ks) {
                // swapped operands: A=codebook, B=x -> C[row=code][col=x-row]
                acc[cf] = __builtin_amdgcn_mfma_f32_16x16x32_bf16(
                    bh[ks], xh[ks], acc[cf], 0, 0, 0);
                acc[cf] = __builtin_amdgcn_mfma_f32_16x16x32_bf16(
                    bh[ks], xl[ks], acc[cf], 0, 0, 0);
            }
        }
        // acc[cf][i] = dist(code t*128 + cf*16 + kg*4 + i, row)

        // ---- epilogue: 31 fmin + 2 shfl + margin append (register rm) ----
        float m = 3.4e38f;
#pragma unroll
        for (int cf = 0; cf < 8; ++cf)
#pragma unroll
            for (int i = 0; i < 4; ++i) m = fminf(m, acc[cf][i]);
        m = fminf(m, __shfl_xor(m, 16));
        m = fminf(m, __shfl_xor(m, 32));  // min over this tile's 128 codes for `row`
        // superset proof (order-free): at winner's tile, approx(w) <= rm+2e < rm+MARGIN
        if (__any(m < rm + MARGIN)) {
            const float thr = fminf(rm, m) + MARGIN;
#pragma unroll
            for (int cf = 0; cf < 8; ++cf)
#pragma unroll
                for (int i = 0; i < 4; ++i) {
                    if (acc[cf][i] < thr) {
                        int p = atomicAdd(&ccnt, 1);
                        if (p < LCAP)
                            clist[p] = (unsigned)((row << 10)
                                                  | (t * TC + cf * 16 + kg * 4 + i));
                    }
                }
        }
        rm = fminf(rm, m);

        __syncthreads();  // drains vmcnt: tile t+1 landed; LDS reads of buf done
    }

    // ---- exact fp32 recheck; packed LDS atomicMin keeps lowest idx on ties ----
    const int nc = (ccnt > LCAP) ? LCAP : ccnt;
    for (int b = wv * 4 + kg; b < nc; b += 16) {  // one candidate per 16-lane group
        const unsigned e = clist[b];
        const int crow = e >> 10, code = e & 1023;
        const float4* xr4 = (const float4*)(x + (size_t)(row0 + crow) * D + la * 8);
        const float4* cr4 = (const float4*)(cb + (size_t)code * D + la * 8);
        float4 a0 = xr4[0], a1 = xr4[1], b0 = cr4[0], b1 = cr4[1];
        float s = a0.x * b0.x;
        s = fmaf(a0.y, b0.y, s); s = fmaf(a0.z, b0.z, s); s = fmaf(a0.w, b0.w, s);
        s = fmaf(a1.x, b1.x, s); s = fmaf(a1.y, b1.y, s);
        s = fmaf(a1.z, b1.z, s); s = fmaf(a1.w, b1.w, s);
#pragma unroll
        for (int off = 1; off <= 8; off <<= 1) s += __shfl_xor(s, off);
        const float dist = fmaf(-2.f, s, cns[code]);
        if (la == 0)
            atomicMin(&win[crow],
                      ((unsigned long long)fenc(dist) << 32) | (unsigned)code);
    }
    __syncthreads();

    // ---- gather: out[row] = cb[winner] (coalesced float4) ----
    {
        const int r = tid >> 2, q = tid & 3;  // 64 rows x 4 chunks of 32 floats
        const int idx = (int)(win[r] & 0xFFFFFFFFull);
        const float4* cs = (const float4*)(cb + (size_t)idx * D + q * 32);
        float4* od = (float4*)(out + (size_t)(row0 + r) * D + q * 32);
#pragma unroll
        for (int i = 0; i < 8; ++i) od[i] = cs[i];
    }
}

extern "C" void kernel_launch(void* const* d_in, const int* in_sizes, int n_in,
                              void* d_out, int out_size, void* d_ws, size_t ws_size,
                              hipStream_t stream) {
    const float* x = (const float*)d_in[0];
    const float* cb = (const float*)d_in[1];
    float* out = (float*)d_out;
    const int N = in_sizes[0] / D;   // 32768
    const int K = in_sizes[1] / D;   // 1024

    float* cnorm = (float*)d_ws;                   // 4 KB
    short* cbh = (short*)((char*)d_ws + 4096);     // 256 KB bf16 fragments

    hipLaunchKernelGGL(prep_kernel, dim3(K * 16 / 256), dim3(256), 0, stream,
                       cb, cnorm, cbh, K);
    hipLaunchKernelGGL(vq_mfma, dim3(N / BR), dim3(NTH), 0, stream,
                       x, cb, cbh, cnorm, out, N, K);
}